// Round 10
// baseline (316.152 us; speedup 1.0000x reference)
//
#include <hip/hip_runtime.h>
#include <stdint.h>
#include <stddef.h>

// ---------------------------------------------------------------------------
// Types / helpers
// ---------------------------------------------------------------------------
using bf16x8 = __attribute__((ext_vector_type(8))) __bf16;
using f32x4  = __attribute__((ext_vector_type(4))) float;
using f32x16 = __attribute__((ext_vector_type(16))) float;

__device__ __forceinline__ float bf2f(unsigned short u) {
  union { unsigned int i; float f; } v; v.i = ((unsigned int)u) << 16; return v.f;
}
__device__ __forceinline__ unsigned short f2bf(float f) {
  union { float f; unsigned int i; } v; v.f = f;
  unsigned int r = v.i + 0x7fffu + ((v.i >> 16) & 1u);   // RNE
  return (unsigned short)(r >> 16);
}
__device__ __forceinline__ unsigned short f2bf_trunc(float f) {
  union { float f; unsigned int i; } v; v.f = f;
  return (unsigned short)(v.i >> 16);
}
// async global->LDS, 16 B/lane; LDS dest must be wave-uniform base + lane*16.
__device__ __forceinline__ void async16(const void* g, void* l) {
  __builtin_amdgcn_global_load_lds(
      (const __attribute__((address_space(1))) unsigned int*)g,
      (__attribute__((address_space(3))) unsigned int*)l, 16, 0, 0);
}

#define S_LEN 2048
#define DMODEL 1024
#define NHEAD 16
#define DHEAD 64
#define DFFN 4096

// ---------------------------------------------------------------------------
// One merged transpose+cast kernel for all 7 weights.
//  u in [0,4096):      wq/wk/wv/wo  (1024x1024 -> T), z = u>>10
//  u in [4096,12288):  w1/w3 -> W13I 32-row interleave, z = (u-4096)>>12
//  u in [12288,16384): w2 (4096x1024 -> T)
// ---------------------------------------------------------------------------
struct TAll {
  const float *wq, *wk, *wv, *wo, *w1, *w3, *w2;
  unsigned short *qkvT, *woT, *w13I, *w2T;
};
__global__ __launch_bounds__(256) void transpose_all_k(TAll j) {
  __shared__ unsigned short tile[32][33];
  const int tx = threadIdx.x & 31;
  const int ty = threadIdx.x >> 5;
  const unsigned u = blockIdx.x;

  const float* in;
  unsigned short* out;
  int bc, br, inC, outR, rs, rb;
  if (u < 4096) {
    int z = u >> 10;
    bc = (u & 31) * 32; br = ((u >> 5) & 31) * 32;
    in = z == 0 ? j.wq : z == 1 ? j.wk : z == 2 ? j.wv : j.wo;
    out = z == 3 ? j.woT : j.qkvT + (size_t)z * 1048576;
    inC = 1024; outR = 1024; rs = 32; rb = 0;      // rs=32,rb=0 with c&31 => identity
  } else if (u < 12288) {
    unsigned v = u - 4096;
    int z = v >> 12;
    bc = (v & 127) * 32; br = ((v >> 7) & 31) * 32;
    in = z ? j.w3 : j.w1;
    out = j.w13I;
    inC = 4096; outR = 1024; rs = 64; rb = z * 32; // dest=(c>>5)*64+rb+(c&31)
  } else {
    unsigned v = u - 12288;
    bc = (v & 31) * 32; br = (v >> 5) * 32;
    in = j.w2; out = j.w2T;
    inC = 1024; outR = 4096; rs = 32; rb = 0;
  }
#pragma unroll
  for (int i = 0; i < 4; ++i)
    tile[ty + i * 8][tx] = f2bf(in[(size_t)(br + ty + i * 8) * inC + bc + tx]);
  __syncthreads();
#pragma unroll
  for (int i = 0; i < 4; ++i) {
    int c = bc + ty + i * 8;
    int dest = (c >> 5) * rs + rb + (c & 31);
    out[(size_t)dest * outR + br + tx] = tile[tx][ty + i * 8];
  }
}

// V region of QKV [s][3072] (cols 2048..3071) -> VtG [c][s]
__global__ __launch_bounds__(256) void vtrans_k(
    const unsigned short* __restrict__ QKV, unsigned short* __restrict__ VtG) {
  __shared__ unsigned short tile[32][33];
  const int tx = threadIdx.x & 31;
  const int ty = threadIdx.x >> 5;
  const int bc = blockIdx.x * 32;
  const int br = blockIdx.y * 32;
#pragma unroll
  for (int i = 0; i < 4; ++i)
    tile[ty + i * 8][tx] = QKV[(size_t)(br + ty + i * 8) * 3072 + 2048 + bc + tx];
  __syncthreads();
#pragma unroll
  for (int i = 0; i < 4; ++i)
    VtG[(size_t)(bc + ty + i * 8) * 2048 + br + tx] = tile[tx][ty + i * 8];
}

// ---------------------------------------------------------------------------
// RMSNorm: f32 X[2048][1024], f32 W -> bf16 Y
// ---------------------------------------------------------------------------
__global__ __launch_bounds__(256) void rmsnorm_k(
    const float* __restrict__ X, const float* __restrict__ W,
    unsigned short* __restrict__ Y) {
  const int row = blockIdx.x;
  const int t = threadIdx.x;
  const int lane = t & 63, w = t >> 6;
  const float* x = X + (size_t)row * DMODEL;
  float xs[4];
  float s = 0.f;
#pragma unroll
  for (int i = 0; i < 4; ++i) {
    xs[i] = x[t * 4 + i];
    s += xs[i] * xs[i];
  }
#pragma unroll
  for (int m = 1; m < 64; m <<= 1) s += __shfl_xor(s, m, 64);
  __shared__ float red[4];
  if (lane == 0) red[w] = s;
  __syncthreads();
  float tot = red[0] + red[1] + red[2] + red[3];
  float inv = rsqrtf(tot * (1.0f / DMODEL) + 1e-6f);
#pragma unroll
  for (int i = 0; i < 4; ++i)
    Y[(size_t)row * DMODEL + t * 4 + i] = f2bf(xs[i] * inv * W[t * 4 + i]);
}

// Fused: h = p0+p1+resid (f32 -> Hres) ; Hin = bf16(rmsnorm(h)*W)
__global__ __launch_bounds__(256) void fused_res_norm_k(
    const float* __restrict__ P0, const float* __restrict__ P1,
    const float* __restrict__ R, const float* __restrict__ W,
    float* __restrict__ Hres, unsigned short* __restrict__ Hin) {
  const int row = blockIdx.x;
  const int t = threadIdx.x;
  const int lane = t & 63, w = t >> 6;
  const size_t base = (size_t)row * DMODEL;
  float hs[4];
  float s = 0.f;
#pragma unroll
  for (int i = 0; i < 4; ++i) {
    int c = t * 4 + i;
    float h = P0[base + c] + P1[base + c] + R[base + c];
    hs[i] = h;
    Hres[base + c] = h;
    s += h * h;
  }
#pragma unroll
  for (int m = 1; m < 64; m <<= 1) s += __shfl_xor(s, m, 64);
  __shared__ float red[4];
  if (lane == 0) red[w] = s;
  __syncthreads();
  float tot = red[0] + red[1] + red[2] + red[3];
  float inv = rsqrtf(tot * (1.0f / DMODEL) + 1e-6f);
#pragma unroll
  for (int i = 0; i < 4; ++i)
    Hin[base + t * 4 + i] = f2bf(hs[i] * inv * W[t * 4 + i]);
}

// ---------------------------------------------------------------------------
// QKV GEMM with fused RoPE epilogue. C[M,3072] = A[M,1024] @ WqkvT^T.
// 128x128 tile, BK=64, mfma_32x32x16, chunk-XOR swizzle.
// Epilogue: Q cols (<1024) roped; K cols (1024..2047) roped * 0.125; V plain.
// ---------------------------------------------------------------------------
__global__ __launch_bounds__(256) void gemm_qkv_rope_k(
    const unsigned short* __restrict__ A,
    const unsigned short* __restrict__ BT,
    unsigned short* __restrict__ C,
    const float* __restrict__ cosp, const float* __restrict__ sinp) {
  __shared__ unsigned short As[128 * 64];
  __shared__ unsigned short Bs[128 * 64];
  const int t = threadIdx.x;
  const int lane = t & 63;
  const int w = t >> 6;
  const int qr = (w >> 1) * 64, qc = (w & 1) * 64;
  const int l31 = lane & 31, half = lane >> 5;
  const int m0 = blockIdx.y * 128, n0 = blockIdx.x * 128;
  const int K = 1024, N = 3072;

  f32x16 acc[2][2] = {};

  for (int k0 = 0; k0 < K; k0 += 64) {
    __syncthreads();
#pragma unroll
    for (int p = 0; p < 4; ++p) {
      int off = p * 2048 + t * 8;
      int r = off >> 6;
      int sc = (((off >> 3) & 7) ^ (r & 7)) * 8;
      async16(A + (size_t)(m0 + r) * K + (k0 + sc), &As[off]);
      async16(BT + (size_t)(n0 + r) * K + (k0 + sc), &Bs[off]);
    }
    __syncthreads();
#pragma unroll
    for (int ks = 0; ks < 4; ++ks) {
      const int ch = ((ks * 2 + half) ^ (l31 & 7)) * 8;
      bf16x8 a0 = *(const bf16x8*)&As[(qr + l31) * 64 + ch];
      bf16x8 a1 = *(const bf16x8*)&As[(qr + 32 + l31) * 64 + ch];
      bf16x8 b0 = *(const bf16x8*)&Bs[(qc + l31) * 64 + ch];
      bf16x8 b1 = *(const bf16x8*)&Bs[(qc + 32 + l31) * 64 + ch];
      acc[0][0] = __builtin_amdgcn_mfma_f32_32x32x16_bf16(a0, b0, acc[0][0], 0, 0, 0);
      acc[0][1] = __builtin_amdgcn_mfma_f32_32x32x16_bf16(a0, b1, acc[0][1], 0, 0, 0);
      acc[1][0] = __builtin_amdgcn_mfma_f32_32x32x16_bf16(a1, b0, acc[1][0], 0, 0, 0);
      acc[1][1] = __builtin_amdgcn_mfma_f32_32x32x16_bf16(a1, b1, acc[1][1], 0, 0, 0);
    }
  }

#pragma unroll
  for (int rt = 0; rt < 2; ++rt)
#pragma unroll
    for (int ct = 0; ct < 2; ++ct) {
      const int colbase = n0 + qc + ct * 32;       // wave-uniform, mult of 32
      const int cc = colbase + l31;
      if (colbase < 2048) {
        // roped region; scale 1 for Q, 0.125 for K (exact pow2)
        const float scale = colbase < 1024 ? 1.0f : 0.125f;
        const int i = (cc & 63) >> 1;
#pragma unroll
        for (int reg = 0; reg < 16; ++reg) {
          int rr = m0 + qr + rt * 32 + (reg & 3) + 8 * (reg >> 2) + 4 * half;
          float v = acc[rt][ct][reg];
          float vp = __shfl_xor(v, 1, 64);
          float c = cosp[rr * 32 + i];
          float sn = sinp[rr * 32 + i];
          float outv = (l31 & 1) ? (vp * sn + v * c) : (v * c - vp * sn);
          C[(size_t)rr * N + cc] = f2bf(outv * scale);
        }
      } else {
#pragma unroll
        for (int reg = 0; reg < 16; ++reg) {
          int rr = m0 + qr + rt * 32 + (reg & 3) + 8 * (reg >> 2) + 4 * half;
          C[(size_t)rr * N + cc] = f2bf(acc[rt][ct][reg]);
        }
      }
    }
}

// ---------------------------------------------------------------------------
// Gated w13 GEMM: 256x128 tile, BK=64, wave = 128x64 (4x2 of 32x32).
// A=Hin [2048][1024], BT=W13I [8192][1024] (32-row interleave), C=F [2048][4096]
// ---------------------------------------------------------------------------
__global__ __launch_bounds__(256) void gemm_gated_k(
    const unsigned short* __restrict__ A,
    const unsigned short* __restrict__ BT,
    unsigned short* __restrict__ C) {
  __shared__ unsigned short As[256 * 64];   // 32 KB
  __shared__ unsigned short Bs[128 * 64];   // 16 KB
  const int t = threadIdx.x;
  const int lane = t & 63;
  const int w = t >> 6;
  const int wm = w >> 1, wn = w & 1;        // wave tile: rows wm*128, cols wn*64
  const int l31 = lane & 31, half = lane >> 5;
  const int m0 = blockIdx.y * 256, n0 = blockIdx.x * 128;
  const int K = 1024;

  f32x16 acc[4][2] = {};

  for (int k0 = 0; k0 < K; k0 += 64) {
    __syncthreads();
#pragma unroll
    for (int p = 0; p < 8; ++p) {           // A: 256x64
      int off = p * 2048 + t * 8;
      int r = off >> 6;
      int sc = (((off >> 3) & 7) ^ (r & 7)) * 8;
      async16(A + (size_t)(m0 + r) * K + (k0 + sc), &As[off]);
    }
#pragma unroll
    for (int p = 0; p < 4; ++p) {           // B: 128x64
      int off = p * 2048 + t * 8;
      int r = off >> 6;
      int sc = (((off >> 3) & 7) ^ (r & 7)) * 8;
      async16(BT + (size_t)(n0 + r) * K + (k0 + sc), &Bs[off]);
    }
    __syncthreads();
#pragma unroll
    for (int ks = 0; ks < 4; ++ks) {
      const int ch = ((ks * 2 + half) ^ (l31 & 7)) * 8;
      bf16x8 b0 = *(const bf16x8*)&Bs[(wn * 64 + l31) * 64 + ch];
      bf16x8 b1 = *(const bf16x8*)&Bs[(wn * 64 + 32 + l31) * 64 + ch];
#pragma unroll
      for (int mt = 0; mt < 4; ++mt) {
        bf16x8 a = *(const bf16x8*)&As[(wm * 128 + mt * 32 + l31) * 64 + ch];
        acc[mt][0] = __builtin_amdgcn_mfma_f32_32x32x16_bf16(a, b0, acc[mt][0], 0, 0, 0);
        acc[mt][1] = __builtin_amdgcn_mfma_f32_32x32x16_bf16(a, b1, acc[mt][1], 0, 0, 0);
      }
    }
  }

  // gated epilogue: acc[mt][0]=g1, acc[mt][1]=g3 for output col (pairing via
  // 32-row interleave of W13I). Output F [2048][4096].
  const int cc = ((n0 + wn * 64) >> 1) + l31;
#pragma unroll
  for (int mt = 0; mt < 4; ++mt)
#pragma unroll
    for (int reg = 0; reg < 16; ++reg) {
      int rr = m0 + wm * 128 + mt * 32 + (reg & 3) + 8 * (reg >> 2) + 4 * half;
      float g1 = acc[mt][0][reg];
      float g3 = acc[mt][1][reg];
      float f = g1 / (1.f + __expf(-g1)) * g3;
      C[(size_t)rr * 4096 + cc] = f2bf(f);
    }
}

// ---------------------------------------------------------------------------
// Split-K GEMM, 64x128 tile, BK=64, mfma_32x32x16, K split 2 (blockIdx.z).
// ---------------------------------------------------------------------------
struct PtrPair { float* p0; float* p1; };

__global__ __launch_bounds__(256) void gemm_bt_sk(
    const unsigned short* __restrict__ A, int lda,
    const unsigned short* __restrict__ BT,
    PtrPair parts, int Kc, int Ktot, int N) {
  __shared__ unsigned short As[64 * 64];
  __shared__ unsigned short Bs[128 * 64];
  const int t = threadIdx.x;
  const int lane = t & 63;
  const int w = t >> 6;
  const int qr = (w >> 1) * 32, qc = (w & 1) * 64;
  const int l31 = lane & 31, half = lane >> 5;
  const int m0 = blockIdx.y * 64, n0 = blockIdx.x * 128;
  const int kb = blockIdx.z * Kc;

  f32x16 acc[2] = {};

  for (int k0 = 0; k0 < Kc; k0 += 64) {
    __syncthreads();
#pragma unroll
    for (int p = 0; p < 2; ++p) {
      int off = p * 2048 + t * 8;
      int r = off >> 6;
      int sc = (((off >> 3) & 7) ^ (r & 7)) * 8;
      async16(A + (size_t)(m0 + r) * lda + (kb + k0 + sc), &As[off]);
    }
#pragma unroll
    for (int p = 0; p < 4; ++p) {
      int off = p * 2048 + t * 8;
      int r = off >> 6;
      int sc = (((off >> 3) & 7) ^ (r & 7)) * 8;
      async16(BT + (size_t)(n0 + r) * Ktot + (kb + k0 + sc), &Bs[off]);
    }
    __syncthreads();
#pragma unroll
    for (int ks = 0; ks < 4; ++ks) {
      const int ch = ((ks * 2 + half) ^ (l31 & 7)) * 8;
      bf16x8 a0 = *(const bf16x8*)&As[(qr + l31) * 64 + ch];
      bf16x8 b0 = *(const bf16x8*)&Bs[(qc + l31) * 64 + ch];
      bf16x8 b1 = *(const bf16x8*)&Bs[(qc + 32 + l31) * 64 + ch];
      acc[0] = __builtin_amdgcn_mfma_f32_32x32x16_bf16(a0, b0, acc[0], 0, 0, 0);
      acc[1] = __builtin_amdgcn_mfma_f32_32x32x16_bf16(a0, b1, acc[1], 0, 0, 0);
    }
  }

  float* C = blockIdx.z ? parts.p1 : parts.p0;
#pragma unroll
  for (int ct = 0; ct < 2; ++ct)
#pragma unroll
    for (int reg = 0; reg < 16; ++reg) {
      int rr = m0 + qr + (reg & 3) + 8 * (reg >> 2) + 4 * half;
      int cc = n0 + qc + ct * 32 + l31;
      C[(size_t)rr * N + cc] = acc[ct][reg];
    }
}

// out = p0 + p1 + resid  (f32, vectorized)
__global__ __launch_bounds__(256) void reduce2_k(
    const float4* __restrict__ P0, const float4* __restrict__ P1,
    const float4* __restrict__ R, float4* __restrict__ Out, int nvec) {
  int i = blockIdx.x * 256 + threadIdx.x;
  if (i >= nvec) return;
  float4 a = P0[i], b = P1[i], r = R[i];
  float4 o;
  o.x = a.x + b.x + r.x;
  o.y = a.y + b.y + r.y;
  o.z = a.z + b.z + r.z;
  o.w = a.w + b.w + r.w;
  Out[i] = o;
}

// ---------------------------------------------------------------------------
// Flash attention, no-max softmax, split-S (blockIdx.z halves of keys).
// ---------------------------------------------------------------------------
#define VPAD 132
__device__ __forceinline__ int swz(int row, int col) { return col ^ ((row & 7) * 8); }

__global__ __launch_bounds__(256) void attn_k(
    const unsigned short* __restrict__ QKV,
    const unsigned short* __restrict__ VtG,
    float* __restrict__ O0, float* __restrict__ O1,
    float* __restrict__ L) {
  const int h = blockIdx.y;
  const int qb = blockIdx.x;
  const int z = blockIdx.z;
  const int t = threadIdx.x;
  const int lane = t & 63;
  const int w = t >> 6;
  const int row16 = lane & 15, quad = lane >> 4;
  const int q0 = qb * 64 + w * 16;
  const int kbase = z * 1024;

  __shared__ unsigned short Ks[128 * 64];
  __shared__ unsigned short Vt[64 * 128];
  __shared__ unsigned short Ps[4][16 * VPAD];

  const unsigned short* Qp = QKV;
  const unsigned short* Kp = QKV + 1024;
  const unsigned short* Vg = VtG + (size_t)h * 64 * 2048;

  bf16x8 aq[2];
#pragma unroll
  for (int kk = 0; kk < 2; ++kk)
    aq[kk] = *(const bf16x8*)(Qp + (size_t)(q0 + row16) * 3072 + h * 64 + kk * 32 + quad * 8);

  f32x4 o[4] = {};
  float l_r[4] = {0.f, 0.f, 0.f, 0.f};

  bf16x8 kreg[4], vreg[4];
#pragma unroll
  for (int p = 0; p < 4; ++p) {
    int off = p * 2048 + t * 8;
    int r = off >> 6, c = off & 63;
    kreg[p] = *(const bf16x8*)(Kp + (size_t)(kbase + r) * 3072 + h * 64 + c);
    int d = off >> 7, key = off & 127;
    vreg[p] = *(const bf16x8*)(Vg + (size_t)d * 2048 + kbase + key);
  }

  for (int kb = kbase; kb < kbase + 1024; kb += 128) {
    __syncthreads();
#pragma unroll
    for (int p = 0; p < 4; ++p) {
      int off = p * 2048 + t * 8;
      int r = off >> 6, c = off & 63;
      *(bf16x8*)&Ks[r * 64 + swz(r, c)] = kreg[p];
      int d = off >> 7, key = off & 127;
      *(bf16x8*)&Vt[d * 128 + swz(d, key)] = vreg[p];
    }
    __syncthreads();
    if (kb + 128 < kbase + 1024) {
      int kb2 = kb + 128;
#pragma unroll
      for (int p = 0; p < 4; ++p) {
        int off = p * 2048 + t * 8;
        int r = off >> 6, c = off & 63;
        kreg[p] = *(const bf16x8*)(Kp + (size_t)(kb2 + r) * 3072 + h * 64 + c);
        int d = off >> 7, key = off & 127;
        vreg[p] = *(const bf16x8*)(Vg + (size_t)d * 2048 + kb2 + key);
      }
    }

    // QK^T (K pre-scaled by 1/8)
    f32x4 sc[8];
#pragma unroll
    for (int tj = 0; tj < 8; ++tj) {
      int kr = tj * 16 + row16;
      bf16x8 b0 = *(const bf16x8*)&Ks[kr * 64 + swz(kr, quad * 8)];
      bf16x8 b1 = *(const bf16x8*)&Ks[kr * 64 + swz(kr, 32 + quad * 8)];
      f32x4 z4 = {};
      z4 = __builtin_amdgcn_mfma_f32_16x16x32_bf16(aq[0], b0, z4, 0, 0, 0);
      z4 = __builtin_amdgcn_mfma_f32_16x16x32_bf16(aq[1], b1, z4, 0, 0, 0);
      sc[tj] = z4;
    }

    // no-max softmax
#pragma unroll
    for (int reg = 0; reg < 4; ++reg) {
      float ssum = 0.f;
#pragma unroll
      for (int tj = 0; tj < 8; ++tj) {
        float p = __expf(sc[tj][reg]);
        sc[tj][reg] = p;
        ssum += p;
      }
#pragma unroll
      for (int m = 1; m < 16; m <<= 1) ssum += __shfl_xor(ssum, m, 16);
      l_r[reg] += ssum;
    }

    // P -> per-wave LDS (truncating bf16)
#pragma unroll
    for (int tj = 0; tj < 8; ++tj)
#pragma unroll
      for (int reg = 0; reg < 4; ++reg)
        Ps[w][(quad * 4 + reg) * VPAD + tj * 16 + row16] = f2bf_trunc(sc[tj][reg]);

    // P @ V
    bf16x8 ap[4];
#pragma unroll
    for (int kk = 0; kk < 4; ++kk)
      ap[kk] = *(const bf16x8*)&Ps[w][row16 * VPAD + kk * 32 + quad * 8];
#pragma unroll
    for (int dt = 0; dt < 4; ++dt) {
      int dr = dt * 16 + row16;
#pragma unroll
      for (int kk = 0; kk < 4; ++kk) {
        bf16x8 bv = *(const bf16x8*)&Vt[dr * 128 + swz(dr, kk * 32 + quad * 8)];
        o[dt] = __builtin_amdgcn_mfma_f32_16x16x32_bf16(ap[kk], bv, o[dt], 0, 0, 0);
      }
    }
  }

  float* Op = z ? O1 : O0;
#pragma unroll
  for (int dt = 0; dt < 4; ++dt)
#pragma unroll
    for (int reg = 0; reg < 4; ++reg)
      Op[(size_t)(q0 + quad * 4 + reg) * DMODEL + h * 64 + dt * 16 + row16] = o[dt][reg];
  if (row16 == 0)
#pragma unroll
    for (int reg = 0; reg < 4; ++reg)
      L[(size_t)(h * 2 + z) * S_LEN + q0 + quad * 4 + reg] = l_r[reg];
}

// Attn = bf16((O0+O1) / (l0+l1)); layout [s][h*64+d]
__global__ __launch_bounds__(256) void attn_combine_k(
    const float4* __restrict__ O0, const float4* __restrict__ O1,
    const float* __restrict__ L, unsigned short* __restrict__ Attn) {
  int i = blockIdx.x * 256 + threadIdx.x;
  int e0 = i * 4;
  int s = e0 >> 10;
  int c = e0 & 1023;
  int h = c >> 6;
  float la = L[(size_t)(h * 2) * S_LEN + s];
  float lb = L[(size_t)(h * 2 + 1) * S_LEN + s];
  float inv = 1.f / (la + lb);
  float4 a = O0[i], b = O1[i];
  ushort4 r;
  r.x = f2bf((a.x + b.x) * inv);
  r.y = f2bf((a.y + b.y) * inv);
  r.z = f2bf((a.z + b.z) * inv);
  r.w = f2bf((a.w + b.w) * inv);
  *(ushort4*)(Attn + e0) = r;
}

// ---------------------------------------------------------------------------
// Launch
// ---------------------------------------------------------------------------
extern "C" void kernel_launch(void* const* d_in, const int* in_sizes, int n_in,
                              void* d_out, int out_size, void* d_ws, size_t ws_size,
                              hipStream_t stream) {
  (void)in_sizes; (void)n_in; (void)out_size; (void)ws_size;
  const float* x    = (const float*)d_in[0];
  const float* fcos = (const float*)d_in[1];
  const float* fsin = (const float*)d_in[2];
  const float* wq   = (const float*)d_in[3];
  const float* wk   = (const float*)d_in[4];
  const float* wv   = (const float*)d_in[5];
  const float* wo   = (const float*)d_in[6];
  const float* w1   = (const float*)d_in[7];
  const float* w2   = (const float*)d_in[8];
  const float* w3   = (const float*)d_in[9];
  const float* anw  = (const float*)d_in[10];
  const float* fnw  = (const float*)d_in[11];
  float* out = (float*)d_out;
  char* ws = (char*)d_ws;

  // ---- workspace layout (bytes), total 71,303,168 ----
  unsigned short* WqkvT = (unsigned short*)(ws + 0);
  unsigned short* VtG   = (unsigned short*)(ws + 0);          // over dead WqkvT
  float*          Lbuf  = (float*)(ws + 4194304);
  unsigned short* WoT   = (unsigned short*)(ws + 6291456);
  unsigned short* QKV   = (unsigned short*)(ws + 8388608);
  unsigned short* Attn  = (unsigned short*)(ws + 20971520);
  float* Oa             = (float*)(ws + 25165824);
  float* Ob             = (float*)(ws + 37748736);
  float* P0a            = (float*)(ws + 8388608);             // over dead QKV
  float* P1a            = (float*)(ws + 25165824);            // over dead Oa
  unsigned short* F     = (unsigned short*)(ws + 0);          // FFN phase, over dead VtG/Lbuf/WoT
  float* P0b            = (float*)(ws + 16777216);
  float* P1b            = (float*)(ws + 25165824);
  unsigned short* Hin   = (unsigned short*)(ws + 33554432);
  float*          Hres  = (float*)        (ws + 37748736);    // over dead Ob
  unsigned short* W13I  = (unsigned short*)(ws + 46137344);
  unsigned short* W2T   = (unsigned short*)(ws + 62914560);

  // all weight transposes in one launch
  transpose_all_k<<<16384, 256, 0, stream>>>(
      TAll{wq, wk, wv, wo, w1, w3, w2, WqkvT, WoT, W13I, W2T});

  // attention branch
  rmsnorm_k<<<2048, 256, 0, stream>>>(x, anw, Hin);
  gemm_qkv_rope_k<<<dim3(24, 16), 256, 0, stream>>>(Hin, WqkvT, QKV, fcos, fsin);
  vtrans_k<<<dim3(32, 64), 256, 0, stream>>>(QKV, VtG);
  attn_k<<<dim3(32, 16, 2), 256, 0, stream>>>(QKV, VtG, Oa, Ob, Lbuf);
  attn_combine_k<<<2048, 256, 0, stream>>>((const float4*)Oa, (const float4*)Ob, Lbuf, Attn);
  gemm_bt_sk<<<dim3(8, 32, 2), 256, 0, stream>>>(Attn, 1024, WoT, PtrPair{P0a, P1a}, 512, 1024, 1024);
  fused_res_norm_k<<<2048, 256, 0, stream>>>(P0a, P1a, x, fnw, Hres, Hin);

  // ffn branch
  gemm_gated_k<<<dim3(64, 8), 256, 0, stream>>>(Hin, W13I, F);
  gemm_bt_sk<<<dim3(8, 32, 2), 256, 0, stream>>>(F, 4096, W2T, PtrPair{P0b, P1b}, 2048, 4096, 1024);
  reduce2_k<<<2048, 256, 0, stream>>>((const float4*)P0b, (const float4*)P1b,
                                      (const float4*)Hres, (float4*)out, 524288);
}